// Round 6
// baseline (2127.016 us; speedup 1.0000x reference)
//
#include <hip/hip_runtime.h>
#include <hip/hip_bf16.h>

#define Tn 1024
#define Bn 64
#define En 128
#define G4 512
#define NEGV -10000.0f

typedef _Float16 h8v __attribute__((ext_vector_type(8)));
typedef short bh8 __attribute__((ext_vector_type(8)));
typedef float fl4 __attribute__((ext_vector_type(4)));

// ---------- bf16 helpers ----------
__device__ __forceinline__ float bf2f(unsigned short u) {
    unsigned int v = ((unsigned int)u) << 16;
    float f;
    __builtin_memcpy(&f, &v, 4);
    return f;
}
__device__ __forceinline__ unsigned short f2bf(float f) {
    unsigned int u;
    __builtin_memcpy(&u, &f, 4);
    u = (u + 0x7fffu + ((u >> 16) & 1u)) >> 16;
    return (unsigned short)u;
}

__device__ __forceinline__ float sigf(float x) { return 1.0f / (1.0f + __expf(-x)); }
__device__ __forceinline__ float tanhfast(float x) { return 1.0f - 2.0f / (1.0f + __expf(2.0f * x)); }

// lgkm-only barrier: LDS visibility without draining vmcnt.
// imm 0xC07F = vmcnt(63) expcnt(7) lgkmcnt(0).
__device__ __forceinline__ void barrier_lds_only() {
    __builtin_amdgcn_s_waitcnt(0xC07F);
    __builtin_amdgcn_s_barrier();
}

// =====================================================================
// K1: input projection via bf16 MFMA (unchanged; writes G as [t][b][g] bf16).
// =====================================================================
__global__ __launch_bounds__(256) void k_inproj(
    const int* __restrict__ sent, const float* __restrict__ embed,
    const float* __restrict__ w_ih_f, const float* __restrict__ b_ih_f, const float* __restrict__ b_hh_f,
    const float* __restrict__ w_ih_b, const float* __restrict__ b_ih_b, const float* __restrict__ b_hh_b,
    unsigned short* __restrict__ G_f, unsigned short* __restrict__ G_b)
{
    __shared__ unsigned short Asm[128][136];
    __shared__ unsigned short Bsm[128][136];
    const int tid = threadIdx.x;
    const int dir = blockIdx.z;
    const float* w_ih = dir ? w_ih_b : w_ih_f;
    const float* bi   = dir ? b_ih_b : b_ih_f;
    const float* bh   = dir ? b_hh_b : b_hh_f;
    unsigned short* Gout = dir ? G_b : G_f;

    const int mt = blockIdx.x, nt = blockIdx.y;
    const int r0 = mt * 128, n0 = nt * 128;

    const int srow = tid >> 1;
    const int ch = (tid & 1) * 64;
    {
        const int rg = r0 + srow;
        const int tt = rg >> 6, bb = rg & 63;
        const int tok = sent[bb * Tn + tt];
        const float* ar = embed + (size_t)tok * En + ch;
        const float* br = w_ih + (size_t)(n0 + srow) * En + ch;
#pragma unroll
        for (int i = 0; i < 64; i += 4) {
            float4 v = *(const float4*)(ar + i);
            *(unsigned*)&Asm[srow][ch + i]     = (unsigned)f2bf(v.x) | ((unsigned)f2bf(v.y) << 16);
            *(unsigned*)&Asm[srow][ch + i + 2] = (unsigned)f2bf(v.z) | ((unsigned)f2bf(v.w) << 16);
            float4 u = *(const float4*)(br + i);
            *(unsigned*)&Bsm[srow][ch + i]     = (unsigned)f2bf(u.x) | ((unsigned)f2bf(u.y) << 16);
            *(unsigned*)&Bsm[srow][ch + i + 2] = (unsigned)f2bf(u.z) | ((unsigned)f2bf(u.w) << 16);
        }
    }
    __syncthreads();

    const int w = tid >> 6, lane = tid & 63;
    const int ln = lane & 15, lq = lane >> 4;
    const int nwb = w * 32;

    fl4 acc[8][2];
#pragma unroll
    for (int mi = 0; mi < 8; ++mi)
#pragma unroll
        for (int ni = 0; ni < 2; ++ni) acc[mi][ni] = (fl4){0.f, 0.f, 0.f, 0.f};

#pragma unroll
    for (int kt = 0; kt < 4; ++kt) {
        const int kc = kt * 32 + lq * 8;
        bh8 a[8], bf[2];
#pragma unroll
        for (int mi = 0; mi < 8; ++mi) a[mi] = *(const bh8*)&Asm[mi * 16 + ln][kc];
#pragma unroll
        for (int ni = 0; ni < 2; ++ni) bf[ni] = *(const bh8*)&Bsm[nwb + ni * 16 + ln][kc];
#pragma unroll
        for (int mi = 0; mi < 8; ++mi)
#pragma unroll
            for (int ni = 0; ni < 2; ++ni)
                acc[mi][ni] = __builtin_amdgcn_mfma_f32_16x16x32_bf16(a[mi], bf[ni], acc[mi][ni], 0, 0, 0);
    }

    float bias[2];
#pragma unroll
    for (int ni = 0; ni < 2; ++ni) {
        int n = n0 + nwb + ni * 16 + ln;
        bias[ni] = bi[n] + bh[n];
    }
#pragma unroll
    for (int mi = 0; mi < 8; ++mi)
#pragma unroll
        for (int ni = 0; ni < 2; ++ni) {
            const int n = n0 + nwb + ni * 16 + ln;
#pragma unroll
            for (int rg = 0; rg < 4; ++rg) {
                const int m = mi * 16 + lq * 4 + rg;
                const size_t r = (size_t)(r0 + m);
                Gout[(r << 9) + n] = f2bf(acc[mi][ni][rg] + bias[ni]);
            }
        }
}

// =====================================================================
// K2: LSTM recurrence on the MATRIX pipe.
// Grid (4 batch-groups, 2 dirs), 512 threads = 8 waves. WG owns 16 batches.
// Per step: gates[512] = W[512x128] x h^T[128x16] via mfma_f32_16x16x32_f16.
//   A = W (register-resident): wave w, q in 0..3 -> m-tile gates q*128+w*16..+16.
//       A-frag lane: W[q*128+w*16+(lane&15)][kt*32+quad*8 .. +8]  (64 VGPRs, loaded once)
//   B = h from LDS [16][136] f16: lane reads h[b=lane&15][kt*32+quad*8 ..+8] (ds_read_b128)
//   C (m89-verified): col=lane&15=batch, row=quad*4+reg=gate-in-tile
//       -> lane owns ALL 4 gates of j=w*16+quad*4+reg for ONE batch b=lane&15.
// G (layout [t][b][g] bf16, unchanged): 4x8B loads/lane, 2-step register pipeline.
// h: one 8B LDS write (f16, double-buffered) + one 8B global store (bf16).
// lgkm-only barrier (one per step): outstanding global ops never drain.
// =====================================================================
__global__ __launch_bounds__(512, 2) void k_lstm(
    const float* __restrict__ whh_f, const float* __restrict__ whh_b,
    const unsigned short* __restrict__ G_f, const unsigned short* __restrict__ G_b,
    unsigned short* __restrict__ h_f, unsigned short* __restrict__ h_b)
{
    const int tid = threadIdx.x;
    const int w = tid >> 6;
    const int lane = tid & 63;
    const int ln = lane & 15;
    const int quad = lane >> 4;
    const int bg = blockIdx.x;          // batch-group 0..3
    const int dir = blockIdx.y;
    const float* whh = dir ? whh_b : whh_f;
    const unsigned short* Gd = dir ? G_b : G_f;
    unsigned short* ho = dir ? h_b : h_f;

    const int bglob = bg * 16 + ln;     // this lane's batch (B-frag row & G row)
    const int jbase = w * 16 + quad * 4; // this lane's 4 h-indices (C rows)

    __shared__ __align__(16) unsigned short hls[2][16][136];   // f16, double-buffered

    // ---- weights (A-frags), loaded once: Wf[q][kt], 8 f16 each = 64 VGPRs ----
    h8v Wf[4][4];
#pragma unroll
    for (int q = 0; q < 4; ++q) {
        const float* wrow = whh + (size_t)(q * 128 + w * 16 + ln) * 128;
#pragma unroll
        for (int kt = 0; kt < 4; ++kt) {
            const float* wp = wrow + kt * 32 + quad * 8;
            float4 x = *(const float4*)wp;
            float4 y = *(const float4*)(wp + 4);
            h8v f;
            f[0] = (_Float16)x.x; f[1] = (_Float16)x.y; f[2] = (_Float16)x.z; f[3] = (_Float16)x.w;
            f[4] = (_Float16)y.x; f[5] = (_Float16)y.y; f[6] = (_Float16)y.z; f[7] = (_Float16)y.w;
            Wf[q][kt] = f;
        }
    }

    // zero h buffer 0 (16*136 ushorts = 1088 dwords)
    for (int i = tid; i < 1088; i += 512) ((unsigned*)&hls[0][0][0])[i] = 0u;
    float c[4] = {0.f, 0.f, 0.f, 0.f};
    __syncthreads();

    const int dt = dir ? -1 : 1;
    int t = dir ? (Tn - 1) : 0;

    // ---- G pipeline: ga = step s, gb = step s+1 ----
    uint2 ga[4], gb[4];
    {
        const unsigned short* gp = Gd + (((size_t)t * Bn + bglob) << 9);
#pragma unroll
        for (int q = 0; q < 4; ++q) ga[q] = *(const uint2*)(gp + q * 128 + jbase);
        const unsigned short* gp2 = Gd + (((size_t)(t + dt) * Bn + bglob) << 9);
#pragma unroll
        for (int q = 0; q < 4; ++q) gb[q] = *(const uint2*)(gp2 + q * 128 + jbase);
    }

    int p = 0;
    for (int s = 0; s < Tn; ++s) {
        // prefetch G for step s+2 (2-step slack; consumed via register dep only)
        uint2 gn[4];
        if (s + 2 < Tn) {
            const unsigned short* gp = Gd + (((size_t)(t + 2 * dt) * Bn + bglob) << 9);
#pragma unroll
            for (int q = 0; q < 4; ++q) gn[q] = *(const uint2*)(gp + q * 128 + jbase);
        }

        // ---- MFMA phase: acc[q][reg] = dot(W[gate], h[b]) ----
        fl4 acc[4];
#pragma unroll
        for (int q = 0; q < 4; ++q) acc[q] = (fl4){0.f, 0.f, 0.f, 0.f};
#pragma unroll
        for (int kt = 0; kt < 4; ++kt) {
            h8v hfrag = *(const h8v*)&hls[p][ln][kt * 32 + quad * 8];
#pragma unroll
            for (int q = 0; q < 4; ++q)
                acc[q] = __builtin_amdgcn_mfma_f32_16x16x32_f16(Wf[q][kt], hfrag, acc[q], 0, 0, 0);
        }

        // ---- activations: lane owns (j = jbase+reg, b = bglob) ----
        float hn[4];
#pragma unroll
        for (int r = 0; r < 4; ++r) {
            const unsigned sh = (r & 1) * 16;
            const unsigned d0 = (r < 2) ? ga[0].x : ga[0].y;
            const unsigned d1 = (r < 2) ? ga[1].x : ga[1].y;
            const unsigned d2 = (r < 2) ? ga[2].x : ga[2].y;
            const unsigned d3 = (r < 2) ? ga[3].x : ga[3].y;
            float pi = acc[0][r] + bf2f((unsigned short)(d0 >> sh));
            float pf = acc[1][r] + bf2f((unsigned short)(d1 >> sh));
            float pg = acc[2][r] + bf2f((unsigned short)(d2 >> sh));
            float po = acc[3][r] + bf2f((unsigned short)(d3 >> sh));
            float iv = sigf(pi), fv = sigf(pf), gv = tanhfast(pg), ov = sigf(po);
            c[r] = fv * c[r] + iv * gv;
            hn[r] = ov * tanhfast(c[r]);
        }

        // ---- h writes: 4 f16 -> LDS (8B), 4 bf16 -> global (8B) ----
        {
            _Float16 q0 = (_Float16)hn[0], q1 = (_Float16)hn[1], q2 = (_Float16)hn[2], q3 = (_Float16)hn[3];
            unsigned short u0, u1, u2, u3;
            __builtin_memcpy(&u0, &q0, 2); __builtin_memcpy(&u1, &q1, 2);
            __builtin_memcpy(&u2, &q2, 2); __builtin_memcpy(&u3, &q3, 2);
            uint2 lv;
            lv.x = (unsigned)u0 | ((unsigned)u1 << 16);
            lv.y = (unsigned)u2 | ((unsigned)u3 << 16);
            *(uint2*)&hls[1 - p][ln][jbase] = lv;

            uint2 gvv;
            gvv.x = (unsigned)f2bf(hn[0]) | ((unsigned)f2bf(hn[1]) << 16);
            gvv.y = (unsigned)f2bf(hn[2]) | ((unsigned)f2bf(hn[3]) << 16);
            *(uint2*)(ho + (((size_t)t * Bn + bglob) << 7) + jbase) = gvv;
        }

        // rotate G pipeline
#pragma unroll
        for (int q = 0; q < 4; ++q) { ga[q] = gb[q]; gb[q] = gn[q]; }

        barrier_lds_only();
        t += dt;
        p ^= 1;
    }
}

// =====================================================================
// K3: feats (unchanged).
// =====================================================================
__global__ __launch_bounds__(256) void k_feats(
    const unsigned short* __restrict__ h_f, const unsigned short* __restrict__ h_b,
    const float* __restrict__ w_out, const float* __restrict__ b_out,
    float* __restrict__ feats)
{
    __shared__ float wl[256][12];
    __shared__ float bl[12];
    const int tid = threadIdx.x;
#pragma unroll
    for (int s = 0; s < 9; ++s) wl[tid][s] = w_out[s * 256 + tid];
#pragma unroll
    for (int s = 9; s < 12; ++s) wl[tid][s] = 0.0f;
    if (tid < 12) bl[tid] = (tid < 9) ? b_out[tid] : 0.0f;
    __syncthreads();

    const int r = blockIdx.x * 256 + tid;
    const unsigned short* hfr = h_f + (size_t)r * 128;
    const unsigned short* hbr = h_b + (size_t)r * 128;
    float acc[12];
#pragma unroll
    for (int k = 0; k < 12; ++k) acc[k] = bl[k];

    for (int ch = 0; ch < 32; ++ch) {
        const unsigned short* src = (ch < 16) ? (hfr + ch * 8) : (hbr + (ch - 16) * 8);
        uint4 hv = *(const uint4*)src;
        unsigned int hw0 = hv.x, hw1 = hv.y, hw2 = hv.z, hw3 = hv.w;
        const int jb = ch * 8;
#pragma unroll
        for (int q = 0; q < 8; ++q) {
            unsigned int word = (q < 2) ? hw0 : ((q < 4) ? hw1 : ((q < 6) ? hw2 : hw3));
            unsigned short hs = (q & 1) ? (unsigned short)(word >> 16) : (unsigned short)(word & 0xffff);
            float hf = bf2f(hs);
            const float* wrp = &wl[jb + q][0];
            float4 w0 = *(const float4*)(wrp);
            float4 w1 = *(const float4*)(wrp + 4);
            float4 w2 = *(const float4*)(wrp + 8);
            acc[0] += hf * w0.x; acc[1] += hf * w0.y; acc[2] += hf * w0.z; acc[3] += hf * w0.w;
            acc[4] += hf * w1.x; acc[5] += hf * w1.y; acc[6] += hf * w1.z; acc[7] += hf * w1.w;
            acc[8] += hf * w2.x; acc[9] += hf * w2.y; acc[10] += hf * w2.z; acc[11] += hf * w2.w;
        }
    }
    float* fr = feats + (size_t)r * 9;
#pragma unroll
    for (int k = 0; k < 9; ++k) fr[k] = acc[k];
}

// =====================================================================
// K4: Viterbi (unchanged).
// =====================================================================
__global__ __launch_bounds__(64) void k_viterbi(
    const float* __restrict__ feats, const float* __restrict__ trans,
    float* __restrict__ out)
{
    __shared__ __align__(16) unsigned char bp[1024 * 16];
    __shared__ float fl[1024 * 9];
    __shared__ float dl[12];
    __shared__ unsigned char pt[1024];

    const int b = blockIdx.x, tid = threadIdx.x;

    for (int i = tid; i < 9216; i += 64) {
        int t = i / 9;
        int n = i - t * 9;
        fl[i] = feats[((size_t)t * 64 + b) * 9 + n];
    }

    float tr[9];
    float trs = -3.0e38f;
    if (tid < 9) {
#pragma unroll
        for (int p = 0; p < 9; ++p) tr[p] = trans[tid * 9 + p];
        trs = trans[8 * 9 + tid];
    }
    if (tid < 12) dl[tid] = (tid == 7) ? 0.0f : NEGV;
    __syncthreads();

    if (tid < 9) {
        for (int t = 0; t < 1024; ++t) {
            float4 d0 = *(const float4*)&dl[0];
            float4 d1 = *(const float4*)&dl[4];
            float d8 = dl[8];
            float dv0 = d0.x, dv1 = d0.y, dv2 = d0.z, dv3 = d0.w;
            float dv4 = d1.x, dv5 = d1.y, dv6 = d1.z, dv7 = d1.w;
            float m = dv0 + tr[0]; int am = 0;
            float v;
            v = dv1 + tr[1]; if (v > m) { m = v; am = 1; }
            v = dv2 + tr[2]; if (v > m) { m = v; am = 2; }
            v = dv3 + tr[3]; if (v > m) { m = v; am = 3; }
            v = dv4 + tr[4]; if (v > m) { m = v; am = 4; }
            v = dv5 + tr[5]; if (v > m) { m = v; am = 5; }
            v = dv6 + tr[6]; if (v > m) { m = v; am = 6; }
            v = dv7 + tr[7]; if (v > m) { m = v; am = 7; }
            v = d8  + tr[8]; if (v > m) { m = v; am = 8; }
            float nd = m + fl[t * 9 + tid];
            dl[tid] = nd;
            bp[t * 16 + tid] = (unsigned char)am;
        }
    }
    float tv = (tid < 9) ? (dl[tid] + trs) : -3.0e38f;
    int bi = tid;
#pragma unroll
    for (int off = 8; off >= 1; off >>= 1) {
        float ov = __shfl_down(tv, off, 64);
        int oi = __shfl_down(bi, off, 64);
        if (ov > tv || (ov == tv && oi < bi)) { tv = ov; bi = oi; }
    }
    int best = __shfl(bi, 0, 64);
    if (tid == 0) out[b] = tv;

    if (tid == 0) {
        int tag = best;
        for (int t0 = 1023; t0 >= 0; t0 -= 8) {
            uint4 rows[8];
#pragma unroll
            for (int i = 0; i < 8; ++i) rows[i] = *(const uint4*)&bp[(t0 - i) * 16];
#pragma unroll
            for (int i = 0; i < 8; ++i) {
                pt[t0 - i] = (unsigned char)tag;
                uint4 rw = rows[i];
                unsigned int sel = (unsigned int)tag >> 2;
                unsigned int word = (sel == 0) ? rw.x : ((sel == 1) ? rw.y : rw.z);
                tag = (int)((word >> ((tag & 3) * 8)) & 0xffu);
            }
        }
    }
    for (int i = tid; i < 1024; i += 64) {
        out[64 + b * 1024 + i] = (float)pt[i];
    }
}

// =====================================================================
extern "C" void kernel_launch(void* const* d_in, const int* in_sizes, int n_in,
                              void* d_out, int out_size, void* d_ws, size_t ws_size,
                              hipStream_t stream) {
    const int*   sent   = (const int*)d_in[0];
    const float* embed  = (const float*)d_in[1];
    const float* w_ih_f = (const float*)d_in[2];
    const float* w_hh_f = (const float*)d_in[3];
    const float* b_ih_f = (const float*)d_in[4];
    const float* b_hh_f = (const float*)d_in[5];
    const float* w_ih_b = (const float*)d_in[6];
    const float* w_hh_b = (const float*)d_in[7];
    const float* b_ih_b = (const float*)d_in[8];
    const float* b_hh_b = (const float*)d_in[9];
    const float* w_out  = (const float*)d_in[10];
    const float* b_out  = (const float*)d_in[11];
    const float* trans  = (const float*)d_in[12];
    float* out = (float*)d_out;

    unsigned short* G_f = (unsigned short*)d_ws;
    unsigned short* G_b = G_f + (size_t)Tn * Bn * G4;
    unsigned short* h_f = G_b + (size_t)Tn * Bn * G4;
    unsigned short* h_b = h_f + (size_t)Tn * Bn * 128;
    float* feats = (float*)(h_b + (size_t)Tn * Bn * 128);

    k_inproj<<<dim3(512, 4, 2), 256, 0, stream>>>(sent, embed,
        w_ih_f, b_ih_f, b_hh_f, w_ih_b, b_ih_b, b_hh_b, G_f, G_b);
    k_lstm<<<dim3(4, 2), 512, 0, stream>>>(w_hh_f, w_hh_b, G_f, G_b, h_f, h_b);
    k_feats<<<256, 256, 0, stream>>>(h_f, h_b, w_out, b_out, feats);
    k_viterbi<<<64, 64, 0, stream>>>(feats, trans, out);
}